// Round 6
// baseline (269.566 us; speedup 1.0000x reference)
//
#include <hip/hip_runtime.h>
#include <hip/hip_bf16.h>

#define NFEAT 50
#define LN_EPS 1e-5f
#define NEG_INF_C (-1000000000.0f)
#define NB 4

typedef __bf16 bf16_t;
typedef __bf16 bf16x8 __attribute__((ext_vector_type(8)));
typedef __bf16 bf16x4 __attribute__((ext_vector_type(4)));
typedef float f32x4 __attribute__((ext_vector_type(4)));

// ws layout:
//   byte 0      attnT [2][64][64] bf16   attnT[t][g][f] = attn[t][f][g], zero-padded
//   byte 16384  WT    [4][64][64] bf16   WT[t*2+i][e][k] = w0[t][i*64+k][e]
//   byte 49152  Ud    [4][2][64][8] f32  gate DIFF matrix (U_t0 - U_t1), A-frag swizzled:
//                 Ud[mm][kc][q*16+l16][j] = Ud[f=mm*16+l16][k=kc*32+q*8+j]
//   byte 65536  constd [1] f32           c0 - c1 = sum((tb0-tb1)*gw)   (gb cancels)

__device__ inline float dot4(f32x4 a, f32x4 b) {
  return a[0]*b[0] + a[1]*b[1] + a[2]*b[2] + a[3]*b[3];
}

__global__ __launch_bounds__(256) void prep_kernel(
    const float* __restrict__ masker, const float* __restrict__ ln_w,
    const float* __restrict__ ln_b, const float* __restrict__ tw,
    bf16_t* __restrict__ ws_attnT, bf16_t* __restrict__ ws_WT)
{
  const int tid = threadIdx.x;
  const int lane = tid & 63;

  // ---- WT staging: 32 blocks x 256 threads x 2 elems = 16384 ----
  const int gidx = blockIdx.x * 256 + tid;
#pragma unroll
  for (int j = 0; j < 2; ++j) {
    int o = gidx * 2 + j;            // ((t*2+i)*64 + e)*64 + k
    int k = o & 63;
    int e = (o >> 6) & 63;
    int ti = o >> 12;                // t*2+i
    ws_WT[o] = (bf16_t)tw[(ti * 64 + k) * 64 + e];
  }

  // ---- attention columns: 128 tasks (t,g), one per wave ----
  const int col = blockIdx.x * 4 + (tid >> 6);  // 0..127
  const int f = lane;
  const bool fv = (f < NFEAT);
  const int t = col >> 6, g = col & 63;
  float val = 0.f;
  if (fv && g < NFEAT) {
    float a0 = masker[((t * 3 + 0) * NFEAT + f) * NFEAT + g];
    float a1 = masker[((t * 3 + 1) * NFEAT + f) * NFEAT + g];
    float a2 = masker[((t * 3 + 2) * NFEAT + f) * NFEAT + g];
    float prod = a0 * a1 * a2;
    val = prod > 0.f ? prod : 0.f;            // relu
  }
  float s = val;
  for (int off = 32; off > 0; off >>= 1) s += __shfl_xor(s, off);
  float mean = s / (float)NFEAT;
  float d = fv ? (val - mean) : 0.f;
  float v2 = d * d;
  for (int off = 32; off > 0; off >>= 1) v2 += __shfl_xor(v2, off);
  float var = v2 / (float)NFEAT;
  float lw = fv ? ln_w[f] : 0.f;
  float lb = fv ? ln_b[f] : 0.f;
  float aln = d * rsqrtf(var + LN_EPS) * lw + lb;
  float logit = aln + ((val != 0.f) ? 0.f : NEG_INF_C) + ((f == g) ? 1.f : 0.f);
  if (!fv) logit = -3.0e38f;
  float mx = logit;
  for (int off = 32; off > 0; off >>= 1) mx = fmaxf(mx, __shfl_xor(mx, off));
  float ex = fv ? expf(logit - mx) : 0.f;
  float se = ex;
  for (int off = 32; off > 0; off >>= 1) se += __shfl_xor(se, off);
  float attn = (fv && g < NFEAT && val != 0.f) ? (ex / se) : 0.f;
  ws_attnT[(t * 64 + g) * 64 + f] = (bf16_t)attn;
}

// Gate-diff precompute, one wave per f: 64 waves over 16 blocks.
// Ud[f][k] = U_0[f][k] - U_1[f][k],  U_t[f][k] = sum_e( W1_t[k,e]*gw[f,e] + W2_t[k,e]*v_t[f,e] ),
// v_t[f][e] = sum_{g<50} attn[t][f][g]*gw[g,e];  constd = sum((tb0-tb1)*gw)  (gb cancels).
__global__ __launch_bounds__(256) void prep2_kernel(
    const float* __restrict__ tw, const float* __restrict__ tb,
    const float* __restrict__ gw, const bf16_t* __restrict__ ws_attnT,
    float* __restrict__ ws_Ud, float* __restrict__ ws_constd)
{
  __shared__ float sv[4][3][64];   // per wave: [0]=v0[e], [1]=v1[e], [2]=gw[f,e]
  __shared__ float sred[4];
  const int tid = threadIdx.x;
  const int lane = tid & 63;
  const int w = tid >> 6;
  const int f = blockIdx.x * 4 + w;   // 0..63

  // ---- phase A: v_t[e], e = lane (coalesced gw, broadcast attnT) ----
  float v0 = 0.f, v1 = 0.f;
  const bf16_t* at0 = ws_attnT + f;              // attnT[0][g][f], stride 64
  const bf16_t* at1 = ws_attnT + 64 * 64 + f;    // attnT[1][g][f]
#pragma unroll 5
  for (int g = 0; g < NFEAT; ++g) {
    float gwv = gw[g * 64 + lane];
    v0 += (float)at0[g * 64] * gwv;
    v1 += (float)at1[g * 64] * gwv;
  }
  sv[w][0][lane] = v0;
  sv[w][1][lane] = v1;
  sv[w][2][lane] = (f < NFEAT) ? gw[f * 64 + lane] : 0.f;
  // same-wave LDS write->read: in-order within a wave, no barrier needed

  // ---- phase B: Ud[k], k = lane ----
  float u = 0.f;
  if (f < NFEAT) {
    const f32x4* W10 = (const f32x4*)(tw + (0 * 64 + lane) * 64);   // t0 W1 row k
    const f32x4* W20 = (const f32x4*)(tw + (1 * 64 + lane) * 64);   // t0 W2
    const f32x4* W11 = (const f32x4*)(tw + (2 * 64 + lane) * 64);   // t1 W1
    const f32x4* W21 = (const f32x4*)(tw + (3 * 64 + lane) * 64);   // t1 W2
    const f32x4* va = (const f32x4*)sv[w][0];
    const f32x4* vb = (const f32x4*)sv[w][1];
    const f32x4* gp = (const f32x4*)sv[w][2];
#pragma unroll
    for (int e4 = 0; e4 < 16; ++e4)
      u += dot4(W10[e4], gp[e4]) - dot4(W11[e4], gp[e4])
         + dot4(W20[e4], va[e4]) - dot4(W21[e4], vb[e4]);
  }
  {
    const int k = lane;
    const int mm = f >> 4, l16r = f & 15, kc = k >> 5, q = (k >> 3) & 3, j = k & 7;
    ws_Ud[(((mm * 2 + kc) * 64) + (q * 16 + l16r)) * 8 + j] = u;
  }

  // ---- constd (block 0 only) ----
  if (blockIdx.x == 0) {
    float c = 0.f;
    for (int i = tid; i < 3200; i += 256)
      c += (tb[i] - tb[3200 + i]) * gw[i];
    for (int off = 32; off > 0; off >>= 1) c += __shfl_xor(c, off);
    if (lane == 0) sred[w] = c;
    __syncthreads();
    if (tid == 0) ws_constd[0] = sred[0] + sred[1] + sred[2] + sred[3];
  }
}

// Barrier-free pipelined main: block = NB consecutive b; wave = e-slice of 16.
// Invariants (WT frags, tb combo, constd) hoisted; feat double-buffered in regs;
// P transposed through wave-private LDS (same-wave lgkmcnt only, no __syncthreads).
__global__ __launch_bounds__(256, 2) void main_kernel(
    const float* __restrict__ feat, const float* __restrict__ tb,
    const bf16_t* __restrict__ ws_attnT, const bf16_t* __restrict__ ws_WT,
    const float* __restrict__ ws_Ud, const float* __restrict__ ws_constd,
    float* __restrict__ out)
{
  __shared__ bf16_t sP[4 * 2 * 16 * 72];   // [wave][t][16 e][72 f'-pitch]
  const int tid = threadIdx.x;
  const int w = tid >> 6;
  const int lane = tid & 63;
  const int l16 = lane & 15;
  const int quad = lane >> 4;
  const int e0 = w * 16;
  const int b0 = blockIdx.x * NB;

  // ---- hoisted invariants ----
  bf16x8 bw1[2][2], bw2[2][2];
#pragma unroll
  for (int t = 0; t < 2; ++t)
#pragma unroll
    for (int kc = 0; kc < 2; ++kc) {
      bw1[t][kc] = *(const bf16x8*)(ws_WT + ((t * 2 + 0) * 64 + e0 + l16) * 64 + kc * 32 + quad * 8);
      bw2[t][kc] = *(const bf16x8*)(ws_WT + ((t * 2 + 1) * 64 + e0 + l16) * 64 + kc * 32 + quad * 8);
    }
  float base[4][4], dd[4][4];
#pragma unroll
  for (int mm = 0; mm < 4; ++mm)
#pragma unroll
    for (int r = 0; r < 4; ++r) {
      const int f = mm * 16 + quad * 4 + r;
      if (f < NFEAT) {
        const int o = f * 64 + e0 + l16;
        float t0v = tb[o], t1v = tb[3200 + o];
        base[mm][r] = t1v; dd[mm][r] = t0v - t1v;
      } else { base[mm][r] = 0.f; dd[mm][r] = 0.f; }
    }
  const float cd = ws_constd[0];

  // ---- preload b0 feat into raw[0] ----
  f32x4 raw[2][4][2][2];
  {
    const float* fb = feat + b0 * 3200;
#pragma unroll
    for (int mm = 0; mm < 4; ++mm) {
      const int fr = mm * 16 + l16;
#pragma unroll
      for (int kc = 0; kc < 2; ++kc) {
        f32x4 x0 = {0.f,0.f,0.f,0.f}, x1 = {0.f,0.f,0.f,0.f};
        if (fr < NFEAT) {
          const f32x4* pa = (const f32x4*)(fb + fr * 64 + kc * 32 + quad * 8);
          x0 = pa[0]; x1 = pa[1];
        }
        raw[0][mm][kc][0] = x0; raw[0][mm][kc][1] = x1;
      }
    }
  }

#pragma unroll
  for (int ib = 0; ib < NB; ++ib) {
    const int b = b0 + ib;
    const int cur = ib & 1, nxt = (ib + 1) & 1;

    // ---- gate-diff dot (fp32 raw x Ud) ----
    float dg = 0.f;
#pragma unroll
    for (int mm = 0; mm < 4; ++mm)
#pragma unroll
      for (int kc = 0; kc < 2; ++kc) {
        const f32x4* up = (const f32x4*)(ws_Ud + (((mm * 2 + kc) * 64) + lane) * 8);
        dg += dot4(raw[cur][mm][kc][0], up[0]) + dot4(raw[cur][mm][kc][1], up[1]);
      }

    // ---- convert to bf16 A-frags (raw[cur] dies here) ----
    bf16x8 A[4][2];
#pragma unroll
    for (int mm = 0; mm < 4; ++mm)
#pragma unroll
      for (int kc = 0; kc < 2; ++kc) {
        f32x4 x0 = raw[cur][mm][kc][0], x1 = raw[cur][mm][kc][1];
        bf16x8 a;
        a[0] = (bf16_t)x0[0]; a[1] = (bf16_t)x0[1]; a[2] = (bf16_t)x0[2]; a[3] = (bf16_t)x0[3];
        a[4] = (bf16_t)x1[0]; a[5] = (bf16_t)x1[1]; a[6] = (bf16_t)x1[2]; a[7] = (bf16_t)x1[3];
        A[mm][kc] = a;
      }

    // ---- prefetch next b's feat (overlaps the MFMA section below) ----
    if (ib + 1 < NB) {
      const float* fb = feat + (b + 1) * 3200;
#pragma unroll
      for (int mm = 0; mm < 4; ++mm) {
        const int fr = mm * 16 + l16;
#pragma unroll
        for (int kc = 0; kc < 2; ++kc) {
          f32x4 x0 = {0.f,0.f,0.f,0.f}, x1 = {0.f,0.f,0.f,0.f};
          if (fr < NFEAT) {
            const f32x4* pa = (const f32x4*)(fb + fr * 64 + kc * 32 + quad * 8);
            x0 = pa[0]; x1 = pa[1];
          }
          raw[nxt][mm][kc][0] = x0; raw[nxt][mm][kc][1] = x1;
        }
      }
    }

    // ---- finish gate: wave-reduce, sigmoid ----
#pragma unroll
    for (int off = 32; off > 0; off >>= 1) dg += __shfl_xor(dg, off);
    dg += cd;
    const float ga0 = 1.f / (1.f + expf(-dg));
    const float ga1 = 1.f - ga0;

    // ---- MFMA section ----
    f32x4 H[2][4];
#pragma unroll
    for (int t = 0; t < 2; ++t) {
      f32x4 P[4];
#pragma unroll
      for (int mm = 0; mm < 4; ++mm) P[mm] = (f32x4){0.f, 0.f, 0.f, 0.f};
#pragma unroll
      for (int kc = 0; kc < 2; ++kc)
#pragma unroll
        for (int mm = 0; mm < 4; ++mm)
          P[mm] = __builtin_amdgcn_mfma_f32_16x16x32_bf16(A[mm][kc], bw2[t][kc], P[mm], 0, 0, 0);

      bf16_t* sp = sP + (w * 2 + t) * (16 * 72);
#pragma unroll
      for (int mm = 0; mm < 4; ++mm) {
        bf16x4 pv;
        pv[0] = (bf16_t)P[mm][0]; pv[1] = (bf16_t)P[mm][1];
        pv[2] = (bf16_t)P[mm][2]; pv[3] = (bf16_t)P[mm][3];
        *(bf16x4*)(sp + l16 * 72 + mm * 16 + quad * 4) = pv;
      }

#pragma unroll
      for (int mm = 0; mm < 4; ++mm) H[t][mm] = (f32x4){0.f, 0.f, 0.f, 0.f};
#pragma unroll
      for (int kc = 0; kc < 2; ++kc)
#pragma unroll
        for (int mm = 0; mm < 4; ++mm)
          H[t][mm] = __builtin_amdgcn_mfma_f32_16x16x32_bf16(A[mm][kc], bw1[t][kc], H[t][mm], 0, 0, 0);

#pragma unroll
      for (int kc = 0; kc < 2; ++kc) {
        const bf16x8 bp = *(const bf16x8*)(sp + l16 * 72 + kc * 32 + quad * 8);
#pragma unroll
        for (int mm = 0; mm < 4; ++mm) {
          const bf16x8 ac = *(const bf16x8*)(ws_attnT + (t * 64 + mm * 16 + l16) * 64 + kc * 32 + quad * 8);
          H[t][mm] = __builtin_amdgcn_mfma_f32_16x16x32_bf16(ac, bp, H[t][mm], 0, 0, 0);
        }
      }
    }

    // ---- epilogue: gate-weighted sum + tb combo, store ----
    float* outb = out + b * 3200;
#pragma unroll
    for (int mm = 0; mm < 4; ++mm)
#pragma unroll
      for (int r = 0; r < 4; ++r) {
        const int f = mm * 16 + quad * 4 + r;
        if (f < NFEAT)
          outb[f * 64 + e0 + l16] =
              ga0 * H[0][mm][r] + ga1 * H[1][mm][r] + fmaf(ga0, dd[mm][r], base[mm][r]);
      }
  }
}

extern "C" void kernel_launch(void* const* d_in, const int* in_sizes, int n_in,
                              void* d_out, int out_size, void* d_ws, size_t ws_size,
                              hipStream_t stream) {
  const float* feat   = (const float*)d_in[0];
  const float* masker = (const float*)d_in[1];
  const float* tw     = (const float*)d_in[2];
  const float* tb     = (const float*)d_in[3];
  const float* lnw    = (const float*)d_in[4];
  const float* lnb    = (const float*)d_in[5];
  const float* gw     = (const float*)d_in[6];
  float* out = (float*)d_out;

  bf16_t* ws_attnT  = (bf16_t*)d_ws;                  // 8192 bf16 (16 KB)
  bf16_t* ws_WT     = ws_attnT + 2 * 64 * 64;         // 16384 bf16 (32 KB, ends 49152)
  float*  ws_Ud     = (float*)((char*)d_ws + 49152);  // 4096 f32 (16 KB)
  float*  ws_constd = (float*)((char*)d_ws + 65536);  // 1 f32

  prep_kernel<<<32, 256, 0, stream>>>(masker, lnw, lnb, tw, ws_attnT, ws_WT);
  prep2_kernel<<<16, 256, 0, stream>>>(tw, tb, gw, ws_attnT, ws_Ud, ws_constd);
  main_kernel<<<4096 / NB, 256, 0, stream>>>(feat, tb, ws_attnT, ws_WT, ws_Ud, ws_constd, out);
}

// Round 7
// 224.009 us; speedup vs baseline: 1.2034x; 1.2034x over previous
//
#include <hip/hip_runtime.h>
#include <hip/hip_bf16.h>

#define NFEAT 50
#define LN_EPS 1e-5f
#define NEG_INF_C (-1000000000.0f)
#define NB 8

typedef __bf16 bf16_t;
typedef __bf16 bf16x8 __attribute__((ext_vector_type(8)));
typedef __bf16 bf16x4 __attribute__((ext_vector_type(4)));
typedef float f32x4 __attribute__((ext_vector_type(4)));

// ws layout:
//   byte 0      attnT [2][64][64] bf16   attnT[t][g][f] = attn[t][f][g], zero-padded
//   byte 16384  WT    [4][64][64] bf16   WT[t*2+i][e][k] = w0[t][i*64+k][e]
//   byte 49152  Ud    [4][2][64][8] f32  gate DIFF matrix (U_t0 - U_t1), A-frag swizzled
//   byte 65536  constd [1] f32           c0 - c1 = sum((tb0-tb1)*gw)   (gb cancels)

__device__ inline float dot4(f32x4 a, f32x4 b) {
  return a[0]*b[0] + a[1]*b[1] + a[2]*b[2] + a[3]*b[3];
}

__global__ __launch_bounds__(256) void prep_kernel(
    const float* __restrict__ masker, const float* __restrict__ ln_w,
    const float* __restrict__ ln_b, const float* __restrict__ tw,
    bf16_t* __restrict__ ws_attnT, bf16_t* __restrict__ ws_WT)
{
  const int tid = threadIdx.x;
  const int lane = tid & 63;

  // ---- WT staging: 32 blocks x 256 threads x 2 elems = 16384 ----
  const int gidx = blockIdx.x * 256 + tid;
#pragma unroll
  for (int j = 0; j < 2; ++j) {
    int o = gidx * 2 + j;            // ((t*2+i)*64 + e)*64 + k
    int k = o & 63;
    int e = (o >> 6) & 63;
    int ti = o >> 12;                // t*2+i
    ws_WT[o] = (bf16_t)tw[(ti * 64 + k) * 64 + e];
  }

  // ---- attention columns: 128 tasks (t,g), one per wave ----
  const int col = blockIdx.x * 4 + (tid >> 6);  // 0..127
  const int f = lane;
  const bool fv = (f < NFEAT);
  const int t = col >> 6, g = col & 63;
  float val = 0.f;
  if (fv && g < NFEAT) {
    float a0 = masker[((t * 3 + 0) * NFEAT + f) * NFEAT + g];
    float a1 = masker[((t * 3 + 1) * NFEAT + f) * NFEAT + g];
    float a2 = masker[((t * 3 + 2) * NFEAT + f) * NFEAT + g];
    float prod = a0 * a1 * a2;
    val = prod > 0.f ? prod : 0.f;            // relu
  }
  float s = val;
  for (int off = 32; off > 0; off >>= 1) s += __shfl_xor(s, off);
  float mean = s / (float)NFEAT;
  float d = fv ? (val - mean) : 0.f;
  float v2 = d * d;
  for (int off = 32; off > 0; off >>= 1) v2 += __shfl_xor(v2, off);
  float var = v2 / (float)NFEAT;
  float lw = fv ? ln_w[f] : 0.f;
  float lb = fv ? ln_b[f] : 0.f;
  float aln = d * rsqrtf(var + LN_EPS) * lw + lb;
  float logit = aln + ((val != 0.f) ? 0.f : NEG_INF_C) + ((f == g) ? 1.f : 0.f);
  if (!fv) logit = -3.0e38f;
  float mx = logit;
  for (int off = 32; off > 0; off >>= 1) mx = fmaxf(mx, __shfl_xor(mx, off));
  float ex = fv ? expf(logit - mx) : 0.f;
  float se = ex;
  for (int off = 32; off > 0; off >>= 1) se += __shfl_xor(se, off);
  float attn = (fv && g < NFEAT && val != 0.f) ? (ex / se) : 0.f;
  ws_attnT[(t * 64 + g) * 64 + f] = (bf16_t)attn;
}

// Gate-diff precompute, one wave per f: 64 waves over 16 blocks.
__global__ __launch_bounds__(256) void prep2_kernel(
    const float* __restrict__ tw, const float* __restrict__ tb,
    const float* __restrict__ gw, const bf16_t* __restrict__ ws_attnT,
    float* __restrict__ ws_Ud, float* __restrict__ ws_constd)
{
  __shared__ float sv[4][3][64];   // per wave: [0]=v0[e], [1]=v1[e], [2]=gw[f,e]
  __shared__ float sred[4];
  const int tid = threadIdx.x;
  const int lane = tid & 63;
  const int w = tid >> 6;
  const int f = blockIdx.x * 4 + w;   // 0..63

  float v0 = 0.f, v1 = 0.f;
  const bf16_t* at0 = ws_attnT + f;              // attnT[0][g][f], stride 64
  const bf16_t* at1 = ws_attnT + 64 * 64 + f;    // attnT[1][g][f]
#pragma unroll 5
  for (int g = 0; g < NFEAT; ++g) {
    float gwv = gw[g * 64 + lane];
    v0 += (float)at0[g * 64] * gwv;
    v1 += (float)at1[g * 64] * gwv;
  }
  sv[w][0][lane] = v0;
  sv[w][1][lane] = v1;
  sv[w][2][lane] = (f < NFEAT) ? gw[f * 64 + lane] : 0.f;
  // same-wave LDS write->read: in-order within a wave, no barrier needed

  float u = 0.f;
  if (f < NFEAT) {
    const f32x4* W10 = (const f32x4*)(tw + (0 * 64 + lane) * 64);
    const f32x4* W20 = (const f32x4*)(tw + (1 * 64 + lane) * 64);
    const f32x4* W11 = (const f32x4*)(tw + (2 * 64 + lane) * 64);
    const f32x4* W21 = (const f32x4*)(tw + (3 * 64 + lane) * 64);
    const f32x4* va = (const f32x4*)sv[w][0];
    const f32x4* vb = (const f32x4*)sv[w][1];
    const f32x4* gp = (const f32x4*)sv[w][2];
#pragma unroll
    for (int e4 = 0; e4 < 16; ++e4)
      u += dot4(W10[e4], gp[e4]) - dot4(W11[e4], gp[e4])
         + dot4(W20[e4], va[e4]) - dot4(W21[e4], vb[e4]);
  }
  {
    const int k = lane;
    const int mm = f >> 4, l16r = f & 15, kc = k >> 5, q = (k >> 3) & 3, j = k & 7;
    ws_Ud[(((mm * 2 + kc) * 64) + (q * 16 + l16r)) * 8 + j] = u;
  }

  if (blockIdx.x == 0) {
    float c = 0.f;
    for (int i = tid; i < 3200; i += 256)
      c += (tb[i] - tb[3200 + i]) * gw[i];
    for (int off = 32; off > 0; off >>= 1) c += __shfl_xor(c, off);
    if (lane == 0) sred[w] = c;
    __syncthreads();
    if (tid == 0) ws_constd[0] = sred[0] + sred[1] + sred[2] + sred[3];
  }
}

// Fused prefetch: load feat rows (fp32), accumulate gate-diff dot against Ud,
// convert to bf16 A-frags. fp32 values are transient (no persistent fp32 buffer).
__device__ __forceinline__ void load_b_frags(
    const float* __restrict__ fb, const float* __restrict__ ws_Ud,
    int l16, int quad, int lane, bf16x8 (&A)[4][2], float& dgout)
{
  float dg = 0.f;
#pragma unroll
  for (int mm = 0; mm < 4; ++mm) {
    const int fr = mm * 16 + l16;
#pragma unroll
    for (int kc = 0; kc < 2; ++kc) {
      f32x4 x0 = {0.f,0.f,0.f,0.f}, x1 = {0.f,0.f,0.f,0.f};
      if (fr < NFEAT) {
        const f32x4* pa = (const f32x4*)(fb + fr * 64 + kc * 32 + quad * 8);
        x0 = pa[0]; x1 = pa[1];
      }
      const f32x4* up = (const f32x4*)(ws_Ud + (((mm * 2 + kc) * 64) + lane) * 8);
      dg += dot4(x0, up[0]) + dot4(x1, up[1]);
      bf16x8 a;
      a[0] = (bf16_t)x0[0]; a[1] = (bf16_t)x0[1]; a[2] = (bf16_t)x0[2]; a[3] = (bf16_t)x0[3];
      a[4] = (bf16_t)x1[0]; a[5] = (bf16_t)x1[1]; a[6] = (bf16_t)x1[2]; a[7] = (bf16_t)x1[3];
      A[mm][kc] = a;
    }
  }
  dgout = dg;
}

// Barrier-free pipelined main: block = NB consecutive b; wave = e-slice of 16.
// WT frags hoisted; A-frags double-buffered in bf16 (gate dot fused at load);
// P transposed through wave-private LDS (same-wave lgkmcnt, no __syncthreads).
__global__ __launch_bounds__(256) void main_kernel(
    const float* __restrict__ feat, const float* __restrict__ tb,
    const bf16_t* __restrict__ ws_attnT, const bf16_t* __restrict__ ws_WT,
    const float* __restrict__ ws_Ud, const float* __restrict__ ws_constd,
    float* __restrict__ out)
{
  __shared__ bf16_t sP[4 * 2 * 16 * 72];   // [wave][t][16 e][72 f'-pitch]
  const int tid = threadIdx.x;
  const int w = tid >> 6;
  const int lane = tid & 63;
  const int l16 = lane & 15;
  const int quad = lane >> 4;
  const int e0 = w * 16;
  const int b0 = blockIdx.x * NB;

  // ---- hoisted invariants (32 VGPRs) ----
  bf16x8 bw1[2][2], bw2[2][2];
#pragma unroll
  for (int t = 0; t < 2; ++t)
#pragma unroll
    for (int kc = 0; kc < 2; ++kc) {
      bw1[t][kc] = *(const bf16x8*)(ws_WT + ((t * 2 + 0) * 64 + e0 + l16) * 64 + kc * 32 + quad * 8);
      bw2[t][kc] = *(const bf16x8*)(ws_WT + ((t * 2 + 1) * 64 + e0 + l16) * 64 + kc * 32 + quad * 8);
    }
  const float cd = ws_constd[0];

  // ---- double-buffered bf16 A-frags + gate partials ----
  bf16x8 Abuf[2][4][2];
  float dgp[2];
  load_b_frags(feat + b0 * 3200, ws_Ud, l16, quad, lane, Abuf[0], dgp[0]);

#pragma unroll
  for (int ib = 0; ib < NB; ++ib) {
    const int b = b0 + ib;
    const int cur = ib & 1, nxt = cur ^ 1;

    // ---- prefetch next b (overlaps this b's gate/MFMA work) ----
    if (ib + 1 < NB)
      load_b_frags(feat + (b + 1) * 3200, ws_Ud, l16, quad, lane, Abuf[nxt], dgp[nxt]);

    // ---- finish gate: wave-reduce, sigmoid(g0-g1) ----
    float dg = dgp[cur];
#pragma unroll
    for (int off = 32; off > 0; off >>= 1) dg += __shfl_xor(dg, off);
    dg += cd;
    const float ga0 = 1.f / (1.f + expf(-dg));
    const float ga1 = 1.f - ga0;

    // ---- MFMA section ----
    f32x4 H[2][4];
#pragma unroll
    for (int t = 0; t < 2; ++t) {
      f32x4 P[4];
#pragma unroll
      for (int mm = 0; mm < 4; ++mm) P[mm] = (f32x4){0.f, 0.f, 0.f, 0.f};
#pragma unroll
      for (int kc = 0; kc < 2; ++kc)
#pragma unroll
        for (int mm = 0; mm < 4; ++mm)
          P[mm] = __builtin_amdgcn_mfma_f32_16x16x32_bf16(Abuf[cur][mm][kc], bw2[t][kc], P[mm], 0, 0, 0);

      bf16_t* sp = sP + (w * 2 + t) * (16 * 72);
#pragma unroll
      for (int mm = 0; mm < 4; ++mm) {
        bf16x4 pv;
        pv[0] = (bf16_t)P[mm][0]; pv[1] = (bf16_t)P[mm][1];
        pv[2] = (bf16_t)P[mm][2]; pv[3] = (bf16_t)P[mm][3];
        *(bf16x4*)(sp + l16 * 72 + mm * 16 + quad * 4) = pv;
      }

#pragma unroll
      for (int mm = 0; mm < 4; ++mm) H[t][mm] = (f32x4){0.f, 0.f, 0.f, 0.f};
#pragma unroll
      for (int kc = 0; kc < 2; ++kc)
#pragma unroll
        for (int mm = 0; mm < 4; ++mm)
          H[t][mm] = __builtin_amdgcn_mfma_f32_16x16x32_bf16(Abuf[cur][mm][kc], bw1[t][kc], H[t][mm], 0, 0, 0);

#pragma unroll
      for (int kc = 0; kc < 2; ++kc) {
        const bf16x8 bp = *(const bf16x8*)(sp + l16 * 72 + kc * 32 + quad * 8);
#pragma unroll
        for (int mm = 0; mm < 4; ++mm) {
          const bf16x8 ac = *(const bf16x8*)(ws_attnT + (t * 64 + mm * 16 + l16) * 64 + kc * 32 + quad * 8);
          H[t][mm] = __builtin_amdgcn_mfma_f32_16x16x32_bf16(ac, bp, H[t][mm], 0, 0, 0);
        }
      }
    }

    // ---- epilogue: gate-weighted sum + tb (L1-hot b-invariant loads), store ----
    float* outb = out + b * 3200;
#pragma unroll
    for (int mm = 0; mm < 4; ++mm)
#pragma unroll
      for (int r = 0; r < 4; ++r) {
        const int f = mm * 16 + quad * 4 + r;
        if (f < NFEAT) {
          const int o = f * 64 + e0 + l16;
          outb[o] = ga0 * (H[0][mm][r] + tb[o]) + ga1 * (H[1][mm][r] + tb[3200 + o]);
        }
      }
  }
}

extern "C" void kernel_launch(void* const* d_in, const int* in_sizes, int n_in,
                              void* d_out, int out_size, void* d_ws, size_t ws_size,
                              hipStream_t stream) {
  const float* feat   = (const float*)d_in[0];
  const float* masker = (const float*)d_in[1];
  const float* tw     = (const float*)d_in[2];
  const float* tb     = (const float*)d_in[3];
  const float* lnw    = (const float*)d_in[4];
  const float* lnb    = (const float*)d_in[5];
  const float* gw     = (const float*)d_in[6];
  float* out = (float*)d_out;

  bf16_t* ws_attnT  = (bf16_t*)d_ws;                  // 8192 bf16 (16 KB)
  bf16_t* ws_WT     = ws_attnT + 2 * 64 * 64;         // 16384 bf16 (32 KB, ends 49152)
  float*  ws_Ud     = (float*)((char*)d_ws + 49152);  // 4096 f32 (16 KB)
  float*  ws_constd = (float*)((char*)d_ws + 65536);  // 1 f32

  prep_kernel<<<32, 256, 0, stream>>>(masker, lnw, lnb, tw, ws_attnT, ws_WT);
  prep2_kernel<<<16, 256, 0, stream>>>(tw, tb, gw, ws_attnT, ws_Ud, ws_constd);
  main_kernel<<<4096 / NB, 256, 0, stream>>>(feat, tb, ws_attnT, ws_WT, ws_Ud, ws_constd, out);
}